// Round 3
// baseline (147.571 us; speedup 1.0000x reference)
//
#include <hip/hip_runtime.h>
#include <hip/hip_bf16.h>

constexpr int B_ = 8;
constexpr int S_ = 512;
constexpr int V_ = 30522;

// Nontemporal float2 load (logits are streamed once, never reused).
static __device__ __forceinline__ float2 ntload2(const float* p) {
    const unsigned long long u =
        __builtin_nontemporal_load(reinterpret_cast<const unsigned long long*>(p));
    float2 r;
    r.x = __uint_as_float((unsigned int)u);
    r.y = __uint_as_float((unsigned int)(u >> 32));
    return r;
}

// ---------------- Kernel 1: masked max-pool over S ----------------
// out[b][v] = max(0, max_{s: mask[b][s]=1} logits[b][s][v])
// mask==0 rows are never read from HBM (~50% traffic saved).
constexpr int K1_BLOCK = 256;
constexpr int K1_VEC   = 2;                               // float2 (V even, rows 8B-aligned)
constexpr int K1_COLS  = K1_BLOCK * K1_VEC;               // 512 columns per block
constexpr int NVCHUNK  = (V_ + K1_COLS - 1) / K1_COLS;    // 60

__global__ __launch_bounds__(K1_BLOCK)
void splade_max_kernel(const float* __restrict__ logits,
                       const int* __restrict__ mask,
                       float* __restrict__ out)
{
    __shared__ int s_idx[S_];
    __shared__ int s_cnt;
    const int b = blockIdx.y;

    // Wave 0 compacts active row indices via ballot prefix — no LDS atomics.
    if (threadIdx.x < 64) {
        const int lane = threadIdx.x;
        int cnt = 0;
        for (int base = 0; base < S_; base += 64) {
            const int m = mask[b * S_ + base + lane] != 0;
            const unsigned long long bal = __ballot(m);
            if (m) s_idx[cnt + (int)__popcll(bal & ((1ull << lane) - 1ull))] = base + lane;
            cnt += (int)__popcll(bal);
        }
        if (lane == 0) s_cnt = cnt;
    }
    __syncthreads();
    const int n = s_cnt;

    const int c0 = (blockIdx.x * K1_BLOCK + threadIdx.x) * K1_VEC;
    if (c0 >= V_) return;                                 // after the only barrier

    const float* base = logits + (size_t)b * S_ * V_ + c0;
    float m0 = 0.0f, m1 = 0.0f;                           // 0-init folds in relu clamp

    // 16 independent 512B/wave loads in flight (8 KB/wave outstanding).
    int j = 0;
    for (; j + 16 <= n; j += 16) {
        float2 x[16];
#pragma unroll
        for (int u = 0; u < 16; ++u)
            x[u] = ntload2(base + (size_t)s_idx[j + u] * V_);
#pragma unroll
        for (int u = 0; u < 16; ++u) {
            m0 = fmaxf(m0, x[u].x);
            m1 = fmaxf(m1, x[u].y);
        }
    }
    for (; j < n; ++j) {
        const float2 x = ntload2(base + (size_t)s_idx[j] * V_);
        m0 = fmaxf(m0, x.x);
        m1 = fmaxf(m1, x.y);
    }
    *reinterpret_cast<float2*>(out + (size_t)b * V_ + c0) = make_float2(m0, m1);
}

// ---------------- Kernel 2: per-row exact top-k threshold + finalize ----------------
// One block (256 threads) per batch row; 120 values register-cached per thread.
// k-th largest (ties counted, = top_values[...,-1]) via 31-step binary search on
// the uint bit pattern (monotone for non-negative floats). Count per step uses
// wave-level ballot+popcount (no shfl chain) and a per-iteration LDS counter
// (pre-zeroed) so each step needs exactly ONE 4-wave barrier.
constexpr int K2_BLOCK = 256;
constexpr int V2   = V_ / 2;                              // 15261 float2 per row
constexpr int NPT2 = (V2 + K2_BLOCK - 1) / K2_BLOCK;      // 60 float2 -> 120 values

__global__ __launch_bounds__(K2_BLOCK)
void splade_topk_kernel(float* __restrict__ vals,
                        const int* __restrict__ topk_ptr)
{
    const int b = blockIdx.x;
    const int k = topk_ptr[0];
    float* row = vals + (size_t)b * V_;

    unsigned int v[2 * NPT2];            // register cache, fully static indexing
#pragma unroll
    for (int i = 0; i < NPT2; ++i) {
        const int idx2 = threadIdx.x + i * K2_BLOCK;
        if (idx2 < V2) {
            const float2 x = *reinterpret_cast<const float2*>(row + 2 * idx2);
            v[2 * i]     = __float_as_uint(x.x);
            v[2 * i + 1] = __float_as_uint(x.y);
        } else {
            v[2 * i] = 0u;
            v[2 * i + 1] = 0u;           // 0 < mid always -> never counted
        }
    }

    __shared__ int s_cnt[32];
    for (int i = threadIdx.x; i < 32; i += K2_BLOCK) s_cnt[i] = 0;
    __syncthreads();

    // invariant: count(bits >= lo) >= k,  count(bits >= hi) < k
    unsigned int lo = 0u, hi = 0x7f800000u;
    for (int it = 0; it < 32; ++it) {
        if (hi - lo <= 1u) break;                          // uniform across block
        const unsigned int mid = lo + ((hi - lo) >> 1);    // mid >= 1
        int c = 0;
#pragma unroll
        for (int i = 0; i < 2 * NPT2; ++i)
            c += (int)__popcll(__ballot(v[i] >= mid));     // wave-uniform count
        if ((threadIdx.x & 63) == 0) atomicAdd(&s_cnt[it], c);
        __syncthreads();                                   // the ONLY barrier per step
        const int cnt = s_cnt[it];
        if (cnt >= k) lo = mid; else hi = mid;
    }

    const unsigned int T = lo;           // exactly the k-th largest value's bits
#pragma unroll
    for (int i = 0; i < NPT2; ++i) {
        const int idx2 = threadIdx.x + i * K2_BLOCK;
        if (idx2 < V2) {
            const unsigned int a = v[2 * i], c = v[2 * i + 1];
            float rx = 0.0f, ry = 0.0f;
            if (a >= T) rx = log1pf(__uint_as_float(a));   // execz-skipped when no lane kept
            if (c >= T) ry = log1pf(__uint_as_float(c));
            *reinterpret_cast<float2*>(row + 2 * idx2) = make_float2(rx, ry);
        }
    }
}

extern "C" void kernel_launch(void* const* d_in, const int* in_sizes, int n_in,
                              void* d_out, int out_size, void* d_ws, size_t ws_size,
                              hipStream_t stream) {
    const float* logits = (const float*)d_in[0];
    const int*   mask   = (const int*)d_in[1];
    const int*   topk   = (const int*)d_in[2];
    float*       out    = (float*)d_out;

    dim3 g1(NVCHUNK, B_);
    splade_max_kernel<<<g1, K1_BLOCK, 0, stream>>>(logits, mask, out);
    splade_topk_kernel<<<B_, K2_BLOCK, 0, stream>>>(out, topk);
}

// Round 4
// 97.324 us; speedup vs baseline: 1.5163x; 1.5163x over previous
//
#include <hip/hip_runtime.h>
#include <hip/hip_bf16.h>

constexpr int B_ = 8;
constexpr int S_ = 512;
constexpr int V_ = 30522;

// ---------------- Kernel 1: masked partial max-pool over an S-chunk ----------------
// bufs[sc][b][v] = max(0, max_{s in chunk sc, mask=1} logits[b][s][v])
// 4 S-chunks -> 4 disjoint output buffers (no atomics, no memset needed).
// mask==0 rows are never read from HBM (~50% traffic saved).
constexpr int K1_BLOCK = 256;
constexpr int K1_VEC   = 2;                               // float2 (V even, rows 8B-aligned)
constexpr int K1_COLS  = K1_BLOCK * K1_VEC;               // 512 columns per block
constexpr int NVCHUNK  = (V_ + K1_COLS - 1) / K1_COLS;    // 60
constexpr int NSCHUNK  = 4;                               // 1920 blocks -> ~30 waves/CU
constexpr int SCHUNK   = S_ / NSCHUNK;                    // 128

__global__ __launch_bounds__(K1_BLOCK)
void splade_max_kernel(const float* __restrict__ logits,
                       const int* __restrict__ mask,
                       float* __restrict__ out,      // chunk 0
                       float* __restrict__ ws)       // chunks 1..3, B_*V_ apart
{
    __shared__ int s_idx[SCHUNK];
    __shared__ int s_cnt;
    const int sc = blockIdx.y;
    const int b  = blockIdx.z;
    const int s0 = sc * SCHUNK;

    // Wave 0 compacts active row indices via ballot prefix — no LDS atomics.
    if (threadIdx.x < 64) {
        const int lane = threadIdx.x;
        int cnt = 0;
        for (int base = 0; base < SCHUNK; base += 64) {
            const int m = mask[b * S_ + s0 + base + lane] != 0;
            const unsigned long long bal = __ballot(m);
            if (m) s_idx[cnt + (int)__popcll(bal & ((1ull << lane) - 1ull))] = base + lane;
            cnt += (int)__popcll(bal);
        }
        if (lane == 0) s_cnt = cnt;
    }
    __syncthreads();
    const int n = s_cnt;

    const int c0 = (blockIdx.x * K1_BLOCK + threadIdx.x) * K1_VEC;
    if (c0 >= V_) return;                                 // after the only barrier

    const float* base = logits + (size_t)(b * S_ + s0) * V_ + c0;
    float m0 = 0.0f, m1 = 0.0f;                           // 0-init folds in relu clamp

    int j = 0;
    for (; j + 8 <= n; j += 8) {                          // 8 loads in flight per wave
        const int i0 = s_idx[j+0], i1 = s_idx[j+1], i2 = s_idx[j+2], i3 = s_idx[j+3];
        const int i4 = s_idx[j+4], i5 = s_idx[j+5], i6 = s_idx[j+6], i7 = s_idx[j+7];
        const float2 x0 = *reinterpret_cast<const float2*>(base + (size_t)i0 * V_);
        const float2 x1 = *reinterpret_cast<const float2*>(base + (size_t)i1 * V_);
        const float2 x2 = *reinterpret_cast<const float2*>(base + (size_t)i2 * V_);
        const float2 x3 = *reinterpret_cast<const float2*>(base + (size_t)i3 * V_);
        const float2 x4 = *reinterpret_cast<const float2*>(base + (size_t)i4 * V_);
        const float2 x5 = *reinterpret_cast<const float2*>(base + (size_t)i5 * V_);
        const float2 x6 = *reinterpret_cast<const float2*>(base + (size_t)i6 * V_);
        const float2 x7 = *reinterpret_cast<const float2*>(base + (size_t)i7 * V_);
        m0 = fmaxf(m0, fmaxf(fmaxf(fmaxf(x0.x, x1.x), fmaxf(x2.x, x3.x)),
                             fmaxf(fmaxf(x4.x, x5.x), fmaxf(x6.x, x7.x))));
        m1 = fmaxf(m1, fmaxf(fmaxf(fmaxf(x0.y, x1.y), fmaxf(x2.y, x3.y)),
                             fmaxf(fmaxf(x4.y, x5.y), fmaxf(x6.y, x7.y))));
    }
    for (; j < n; ++j) {
        const float2 x = *reinterpret_cast<const float2*>(base + (size_t)s_idx[j] * V_);
        m0 = fmaxf(m0, x.x);
        m1 = fmaxf(m1, x.y);
    }
    float* dst = (sc == 0) ? out : ws + (size_t)(sc - 1) * B_ * V_;
    *reinterpret_cast<float2*>(dst + (size_t)b * V_ + c0) = make_float2(m0, m1);
}

// ---------------- Kernel 2: merge partials + exact top-k threshold + finalize ----
// One 1024-thread block per batch row; 30 values register-cached per thread
// (proven no-spill config). k-th largest (ties counted, = top_values[...,-1]) via
// 31-step binary search on the uint bit pattern; count via ballot+popc with a
// per-iteration pre-zeroed LDS counter -> ONE barrier per step.
constexpr int K2_BLOCK = 1024;
constexpr int NPT = (V_ + K2_BLOCK - 1) / K2_BLOCK;       // 30

__global__ __launch_bounds__(K2_BLOCK)
void splade_topk_kernel(float* __restrict__ out,          // chunk 0 partial -> final
                        const float* __restrict__ ws,     // chunks 1..3 partials
                        const int* __restrict__ topk_ptr)
{
    const int b = blockIdx.x;
    const int k = topk_ptr[0];
    float* row = out + (size_t)b * V_;
    const float* p1 = ws + (size_t)b * V_;
    const float* p2 = ws + (size_t)(B_ + b) * V_;
    const float* p3 = ws + (size_t)(2 * B_ + b) * V_;

    unsigned int v[NPT];                 // register cache, static indexing only
#pragma unroll
    for (int i = 0; i < NPT; ++i) {
        const int idx = threadIdx.x + i * K2_BLOCK;
        float m = 0.0f;
        if (idx < V_)
            m = fmaxf(fmaxf(row[idx], p1[idx]), fmaxf(p2[idx], p3[idx]));
        v[i] = __float_as_uint(m);       // all partials >= 0 -> uint order == float order
    }

    __shared__ int s_cnt[32];
    for (int i = threadIdx.x; i < 32; i += K2_BLOCK) s_cnt[i] = 0;
    __syncthreads();

    // invariant: count(bits >= lo) >= k,  count(bits >= hi) < k
    unsigned int lo = 0u, hi = 0x7f800000u;
    for (int it = 0; it < 32; ++it) {
        if (hi - lo <= 1u) break;                          // uniform across block
        const unsigned int mid = lo + ((hi - lo) >> 1);    // mid >= 1, OOB zeros never count
        int c = 0;
#pragma unroll
        for (int i = 0; i < NPT; ++i)
            c += (int)__popcll(__ballot(v[i] >= mid));     // wave-uniform count
        if ((threadIdx.x & 63) == 0) atomicAdd(&s_cnt[it], c);
        __syncthreads();                                   // the ONLY barrier per step
        const int cnt = s_cnt[it];
        if (cnt >= k) lo = mid; else hi = mid;
    }

    const unsigned int T = lo;           // exactly the k-th largest value's bits
#pragma unroll
    for (int i = 0; i < NPT; ++i) {
        const int idx = threadIdx.x + i * K2_BLOCK;
        if (idx < V_) {
            const float m = __uint_as_float(v[i]);
            row[idx] = (v[i] >= T) ? log1pf(m) : 0.0f;
        }
    }
}

extern "C" void kernel_launch(void* const* d_in, const int* in_sizes, int n_in,
                              void* d_out, int out_size, void* d_ws, size_t ws_size,
                              hipStream_t stream) {
    const float* logits = (const float*)d_in[0];
    const int*   mask   = (const int*)d_in[1];
    const int*   topk   = (const int*)d_in[2];
    float*       out    = (float*)d_out;
    float*       ws     = (float*)d_ws;
    // needs 3 partial buffers in ws: 3 * 8 * 30522 * 4 B = 2.93 MB (ws is far larger)

    dim3 g1(NVCHUNK, NSCHUNK, B_);
    splade_max_kernel<<<g1, K1_BLOCK, 0, stream>>>(logits, mask, out, ws);
    splade_topk_kernel<<<B_, K2_BLOCK, 0, stream>>>(out, ws, topk);
}

// Round 5
// 82.827 us; speedup vs baseline: 1.7817x; 1.1750x over previous
//
#include <hip/hip_runtime.h>
#include <hip/hip_bf16.h>

constexpr int B_  = 8;
constexpr int S_  = 512;
constexpr int V_  = 30522;
constexpr int V2_ = V_ / 2;                      // 15261 float2 per row (V even)

// ---------------- Kernel 1: masked partial max-pool, row-streaming ----------------
// Block (vs, g, b) streams CONTIGUOUS 30.5 KB slices [vs] of every active row in
// group g (compacted rows g, g+NS, ...), keeping the running max in registers.
// Fat sequential reads instead of thin 2 KB gathers -> DRAM-friendly streams.
constexpr int K1_THREADS = 1024;
constexpr int VSPLIT  = 4;
constexpr int VSLICE  = 7632;                    // even; 4*7632 >= V_
constexpr int VSLICE2 = VSLICE / 2;              // 3816 float2 per slice
constexpr int NS      = 16;                      // row groups -> 512 blocks total
constexpr int NSLOT   = 4;                       // 4*1024 float2 slots >= 3816

__global__ __launch_bounds__(K1_THREADS)
void splade_partial_max(const float* __restrict__ logits,
                        const int* __restrict__ mask,
                        float* __restrict__ partial)     // [NS][B][V] in ws
{
    __shared__ int s_idx[S_];
    __shared__ int s_cnt;
    const int vs = blockIdx.x;
    const int g  = blockIdx.y;
    const int b  = blockIdx.z;

    // Wave 0 compacts active row indices via ballot prefix (no LDS atomics).
    if (threadIdx.x < 64) {
        const int lane = threadIdx.x;
        int cnt = 0;
        for (int base = 0; base < S_; base += 64) {
            const int m = mask[b * S_ + base + lane] != 0;
            const unsigned long long bal = __ballot(m);
            if (m) s_idx[cnt + (int)__popcll(bal & ((1ull << lane) - 1ull))] = base + lane;
            cnt += (int)__popcll(bal);
        }
        if (lane == 0) s_cnt = cnt;
    }
    __syncthreads();
    const int n = s_cnt;

    // Per-slot float2 column index within the row (clamped safe address).
    int  colf2[NSLOT];
    bool valid[NSLOT];
#pragma unroll
    for (int p = 0; p < NSLOT; ++p) {
        const int idx2 = threadIdx.x + p * K1_THREADS;   // float2 idx within slice
        const int cf2  = vs * VSLICE2 + idx2;
        valid[p] = (idx2 < VSLICE2) && (cf2 < V2_);
        colf2[p] = valid[p] ? cf2 : (V2_ - 1);
    }

    float2 acc[NSLOT];
#pragma unroll
    for (int p = 0; p < NSLOT; ++p) acc[p] = make_float2(0.0f, 0.0f);  // relu folded in

    const float2* lg = reinterpret_cast<const float2*>(logits);

    int r = g;
    for (; r + NS < n; r += 2 * NS) {                    // 2-row pipeline: 8 loads in flight
        const int s0 = s_idx[r], s1 = s_idx[r + NS];
        const float2* row0 = lg + (size_t)(b * S_ + s0) * V2_;
        const float2* row1 = lg + (size_t)(b * S_ + s1) * V2_;
        float2 x0[NSLOT], x1[NSLOT];
#pragma unroll
        for (int p = 0; p < NSLOT; ++p) x0[p] = row0[colf2[p]];
#pragma unroll
        for (int p = 0; p < NSLOT; ++p) x1[p] = row1[colf2[p]];
#pragma unroll
        for (int p = 0; p < NSLOT; ++p) {
            acc[p].x = fmaxf(acc[p].x, fmaxf(x0[p].x, x1[p].x));
            acc[p].y = fmaxf(acc[p].y, fmaxf(x0[p].y, x1[p].y));
        }
    }
    if (r < n) {                                         // odd tail row
        const float2* row0 = lg + (size_t)(b * S_ + s_idx[r]) * V2_;
        float2 x0[NSLOT];
#pragma unroll
        for (int p = 0; p < NSLOT; ++p) x0[p] = row0[colf2[p]];
#pragma unroll
        for (int p = 0; p < NSLOT; ++p) {
            acc[p].x = fmaxf(acc[p].x, x0[p].x);
            acc[p].y = fmaxf(acc[p].y, x0[p].y);
        }
    }

    float2* dst = reinterpret_cast<float2*>(partial) + ((size_t)g * B_ + b) * V2_;
#pragma unroll
    for (int p = 0; p < NSLOT; ++p)
        if (valid[p]) dst[colf2[p]] = acc[p];
}

// ---------------- Kernel M: WIDE merge of NS partials -> out ----------------
// 480 blocks; k2 must never read the 15.6 MB of partials (8-CU bandwidth trap).
constexpr int KM_THREADS  = 256;
constexpr int KM_BLOCKS_X = (V2_ + KM_THREADS - 1) / KM_THREADS;   // 60

__global__ __launch_bounds__(KM_THREADS)
void splade_merge(const float* __restrict__ partial, float* __restrict__ out)
{
    const int b    = blockIdx.y;
    const int idx2 = blockIdx.x * KM_THREADS + threadIdx.x;
    if (idx2 >= V2_) return;
    const float2* p0 = reinterpret_cast<const float2*>(partial) + (size_t)b * V2_ + idx2;
    float2 m = make_float2(0.0f, 0.0f);
#pragma unroll
    for (int gg = 0; gg < NS; ++gg) {
        const float2 x = p0[(size_t)gg * B_ * V2_];
        m.x = fmaxf(m.x, x.x);
        m.y = fmaxf(m.y, x.y);
    }
    reinterpret_cast<float2*>(out)[(size_t)b * V2_ + idx2] = m;
}

// ---------------- Kernel 2: per-row exact top-k threshold + finalize ----------------
// One 1024-thread block per batch row; reads ONLY the final 1 MB (float2 loads).
// k-th largest (ties counted, = top_values[...,-1]) via binary search on the uint
// bit pattern; ballot+popc counts, one barrier per step (proven in round 4).
constexpr int K2_BLOCK = 1024;
constexpr int NPT2 = (V2_ + K2_BLOCK - 1) / K2_BLOCK;    // 15 float2 -> 30 uints

__global__ __launch_bounds__(K2_BLOCK)
void splade_topk_kernel(float* __restrict__ out,
                        const int* __restrict__ topk_ptr)
{
    const int b = blockIdx.x;
    const int k = topk_ptr[0];
    float2* row2 = reinterpret_cast<float2*>(out) + (size_t)b * V2_;

    unsigned int v[2 * NPT2];            // register cache, static indexing only
#pragma unroll
    for (int i = 0; i < NPT2; ++i) {
        const int idx2 = threadIdx.x + i * K2_BLOCK;
        float2 x = make_float2(0.0f, 0.0f);              // OOB zeros never counted
        if (idx2 < V2_) x = row2[idx2];
        v[2 * i]     = __float_as_uint(x.x);
        v[2 * i + 1] = __float_as_uint(x.y);
    }

    __shared__ int s_cnt[32];
    for (int i = threadIdx.x; i < 32; i += K2_BLOCK) s_cnt[i] = 0;
    __syncthreads();

    // invariant: count(bits >= lo) >= k,  count(bits >= hi) < k
    unsigned int lo = 0u, hi = 0x7f800000u;
    for (int it = 0; it < 32; ++it) {
        if (hi - lo <= 1u) break;                        // uniform across block
        const unsigned int mid = lo + ((hi - lo) >> 1);  // mid >= 1
        int c = 0;
#pragma unroll
        for (int i = 0; i < 2 * NPT2; ++i)
            c += (int)__popcll(__ballot(v[i] >= mid));   // wave-uniform count
        if ((threadIdx.x & 63) == 0) atomicAdd(&s_cnt[it], c);
        __syncthreads();                                 // the ONLY barrier per step
        const int cnt = s_cnt[it];
        if (cnt >= k) lo = mid; else hi = mid;
    }

    const unsigned int T = lo;           // exactly the k-th largest value's bits
#pragma unroll
    for (int i = 0; i < NPT2; ++i) {
        const int idx2 = threadIdx.x + i * K2_BLOCK;
        if (idx2 < V2_) {
            const unsigned int a = v[2 * i], c = v[2 * i + 1];
            float rx = 0.0f, ry = 0.0f;
            if (a >= T) rx = log1pf(__uint_as_float(a));
            if (c >= T) ry = log1pf(__uint_as_float(c));
            row2[idx2] = make_float2(rx, ry);
        }
    }
}

extern "C" void kernel_launch(void* const* d_in, const int* in_sizes, int n_in,
                              void* d_out, int out_size, void* d_ws, size_t ws_size,
                              hipStream_t stream) {
    const float* logits = (const float*)d_in[0];
    const int*   mask   = (const int*)d_in[1];
    const int*   topk   = (const int*)d_in[2];
    float*       out    = (float*)d_out;
    float*       ws     = (float*)d_ws;   // needs NS*B*V*4 = 15.6 MB of scratch

    dim3 g1(VSPLIT, NS, B_);
    splade_partial_max<<<g1, K1_THREADS, 0, stream>>>(logits, mask, ws);
    dim3 gm(KM_BLOCKS_X, B_);
    splade_merge<<<gm, KM_THREADS, 0, stream>>>(ws, out);
    splade_topk_kernel<<<B_, K2_BLOCK, 0, stream>>>(out, topk);
}